// Round 7
// baseline (62.643 us; speedup 1.0000x reference)
//
#include <hip/hip_runtime.h>

// VQ-VAE quantizer: x[32][64][64][64] f32 NCHW, embed[1024][64] f32
// out: z_q (8388608 f32, NCHW) ++ loss (1 f32),  loss = 1.25*mean((z_q-z)^2)
//
// Block = 4 waves, 4 h-rows (256 positions); wave owns 64 positions (nt=4) so
// each A-frag ds_read feeds 8 MFMA (R6's nt=2 was LDS-pipe-bound: 3 b128 per
// 4 MFMA). Codebook streamed through LDS in 8 chunks of 128 codes, double-
// buffered via global_load_lds DMA (zero VGPR staging; register-staged
// codebook spilled in R2/R3/R5). eb PRE-SWIZZLED so linear DMA dest ==
// swizzled ds_read layout. Loss from winning keys (no epilogue x re-read).
// Epilogue stores coalesced in 256B segments (R6's 16B/lane scatter caused
// 1.75x write amplification).

#define TOTAL_ELEMS 8388608
#define LOSS_SCALE (1.25f / 8388608.f)

typedef float  f32x4  __attribute__((ext_vector_type(4)));
typedef __bf16 bf16x8 __attribute__((ext_vector_type(8)));
typedef unsigned int u32x4 __attribute__((ext_vector_type(4)));

static __device__ __forceinline__ unsigned short f2bf(float f) {
    unsigned int u = __float_as_uint(f);
    u += 0x7FFFu + ((u >> 16) & 1u);   // round-to-nearest-even
    return (unsigned short)(u >> 16);
}

static __device__ __forceinline__ void gload_lds16(const void* g, void* l) {
    __builtin_amdgcn_global_load_lds(
        (const __attribute__((address_space(1))) void*)g,
        (__attribute__((address_space(3))) void*)l,
        16, 0, 0);
}

// ---- prep: embed f32 -> bf16 PRE-SWIZZLED + c0 = 0.25 - 0.5*||e||^2 ----
__global__ void vq_prep(const float* __restrict__ embed,
                        unsigned short* __restrict__ eb,
                        float* __restrict__ c0,
                        float* __restrict__ loss_slot) {
    int t   = blockIdx.x * 256 + threadIdx.x;   // 0..4095
    int row = t >> 2, qd = t & 3;
    const float* src = embed + row * 64 + qd * 16;
    float s = 0.f;
    unsigned short tmp[16];
#pragma unroll
    for (int i = 0; i < 4; i++) {
        f32x4 v = *(const f32x4*)(src + i * 4);
#pragma unroll
        for (int j = 0; j < 4; j++) {
            float f = v[j];
            s += f * f;
            tmp[i * 4 + j] = f2bf(f);
        }
    }
    u32x4 w0, w1;
#pragma unroll
    for (int i = 0; i < 4; i++) {
        w0[i] = (unsigned)tmp[2*i]   | ((unsigned)tmp[2*i+1] << 16);
        w1[i] = (unsigned)tmp[8+2*i] | ((unsigned)tmp[8+2*i+1] << 16);
    }
    // swizzled store: element (row, byte k2) lives at row*128 + (k2 ^ ((row&7)<<4))
    char* dstb = (char*)eb + row * 128;
    const int sw = (row & 7) << 4;
    *(u32x4*)(dstb + ((qd * 32) ^ sw))      = w0;
    *(u32x4*)(dstb + ((qd * 32 + 16) ^ sw)) = w1;
    s += __shfl_xor(s, 1);
    s += __shfl_xor(s, 2);
    if (qd == 0) c0[row] = 0.25f - 0.5f * s;    // MFMA C-init: acc = z.e + c0 > 0
    if (t == 0) *loss_slot = 0.f;
}

// argmin dist == argmax acc (acc = z.e + 0.25 - ||e||^2/2, strictly positive)
// key = (bits(acc) & ~1023) | (1023 - code)  -> pure u32 max chain
__global__ __launch_bounds__(256, 2) void vq_main(
    const float* __restrict__ x,
    const float* __restrict__ embed,            // f32, for exact gather
    const unsigned short* __restrict__ eb,      // bf16, pre-swizzled rows
    const float* __restrict__ c0,               // f32 per-code C-init
    float* __restrict__ out,
    float* __restrict__ loss) {

    __shared__ __align__(16) unsigned char zbuf[32768];     // z-tile [pos][k]
    __shared__ __align__(16) unsigned char dbuf[2][16384];  // cb chunk dbuf
    __shared__ __align__(16) float c0l[1024];
    __shared__ int   idxf[256];
    __shared__ float lpart[4];

    const int t    = threadIdx.x;
    const int wv   = t >> 6, lane = t & 63;
    const int l15  = lane & 15, lq = lane >> 4;

    const int blk = blockIdx.x;                  // 0..511 = 32 b x 16 h-groups
    const int b   = blk >> 4;
    const int h0  = (blk & 15) * 4;
    const size_t xbase = (size_t)b * 262144 + (size_t)h0 * 64;

    const char* ebp = (const char*)eb;

    // ---- chunk 0 DMA -> dbuf[0] (async, no VGPRs) ----
#pragma unroll
    for (int s = 0; s < 4; s++)
        gload_lds16(ebp + (wv * 4 + s) * 1024 + lane * 16,
                    &dbuf[0][(wv * 4 + s) * 1024]);

    // ---- c0 -> LDS (4 KB) ----
    *(f32x4*)(c0l + t * 4) = *(const f32x4*)(c0 + t * 4);

    // ---- stage z -> zbuf: thread = channels {2c2,2c2+1} x 32 w; z^2 partial ----
    const int c2 = t & 31, g = t >> 5;
    const int hh = g >> 1, w32 = (g & 1) * 32;
    float part = 0.f;
#pragma unroll
    for (int i = 0; i < 8; i++) {
        int w = w32 + i * 4;
        f32x4 v0 = *(const f32x4*)(x + xbase + (size_t)(2 * c2) * 4096 + hh * 64 + w);
        f32x4 v1 = *(const f32x4*)(x + xbase + (size_t)(2 * c2 + 1) * 4096 + hh * 64 + w);
#pragma unroll
        for (int j = 0; j < 4; j++) {
            int pos = hh * 64 + w + j;
            unsigned int val = (unsigned int)f2bf(v0[j]) | ((unsigned int)f2bf(v1[j]) << 16);
            part += v0[j] * v0[j] + v1[j] * v1[j];
            *(unsigned int*)(&zbuf[pos * 128 + ((c2 * 4) ^ ((pos & 7) << 4))]) = val;
        }
    }
    __syncthreads();                             // z + chunk0 DMA + c0l complete

    // ---- B-frags for this wave's 64 positions (32 VGPR, resident) ----
    bf16x8 bfr[4][2];
#pragma unroll
    for (int nt = 0; nt < 4; nt++) {
        int pos = wv * 64 + nt * 16 + l15;
        int rb  = pos * 128, sw = (pos & 7) << 4;
        bfr[nt][0] = *(const bf16x8*)(&zbuf[rb + ((lq * 16) ^ sw)]);
        bfr[nt][1] = *(const bf16x8*)(&zbuf[rb + ((64 + lq * 16) ^ sw)]);
    }

    // ---- 8 chunks x (8 mt x 4 nt x 2 MFMA), depth-1 DMA prefetch ----
    unsigned int key[4] = {0u, 0u, 0u, 0u};
#pragma unroll
    for (int ch = 0; ch < 8; ch++) {
        const int cur = ch & 1;
        if (ch < 7) {                            // DMA next chunk into other buf
#pragma unroll
            for (int s = 0; s < 4; s++)
                gload_lds16(ebp + (ch + 1) * 16384 + (wv * 4 + s) * 1024 + lane * 16,
                            &dbuf[cur ^ 1][(wv * 4 + s) * 1024]);
        }
        const int invc = 1023 - ch * 128 - lq * 4;
#pragma unroll
        for (int mt = 0; mt < 8; mt++) {
            int rb = (mt * 16 + l15) * 128, sw = (l15 & 7) << 4;
            bf16x8 a0 = *(const bf16x8*)(&dbuf[cur][rb + ((lq * 16) ^ sw)]);
            bf16x8 a1 = *(const bf16x8*)(&dbuf[cur][rb + ((64 + lq * 16) ^ sw)]);
            f32x4 c0v = *(const f32x4*)(c0l + ch * 128 + mt * 16 + lq * 4);  // broadcast
            const int invm = invc - mt * 16;
#pragma unroll
            for (int nt = 0; nt < 4; nt++) {
                f32x4 acc = __builtin_amdgcn_mfma_f32_16x16x32_bf16(a0, bfr[nt][0], c0v, 0, 0, 0);
                acc = __builtin_amdgcn_mfma_f32_16x16x32_bf16(a1, bfr[nt][1], acc, 0, 0, 0);
                // D: col(l15)=pos-in-16-tile, row=(lq*4+r)=code-in-16-tile
#pragma unroll
                for (int r = 0; r < 4; r++) {
                    unsigned int k2 = (__float_as_uint(acc[r]) & 0xFFFFFC00u)
                                    | (unsigned int)(invm - r);
                    key[nt] = key[nt] > k2 ? key[nt] : k2;
                }
            }
        }
        if (ch < 7) __syncthreads();             // drains DMA; guards buf reuse
    }

    // ---- wave-local argmax; loss contribution from keys ----
#pragma unroll
    for (int nt = 0; nt < 4; nt++) {
        unsigned int k = key[nt];
        unsigned int o = (unsigned int)__shfl_xor((int)k, 16); k = k > o ? k : o;
        o = (unsigned int)__shfl_xor((int)k, 32);              k = k > o ? k : o;
        // every lane holds the final key for position (wv*64 + nt*16 + l15);
        // acc appears 4x per wave (lq replication): weight -2/4 = -0.5
        part -= 0.5f * __uint_as_float(k & 0xFFFFFC00u);
        if (lane < 16) idxf[wv * 64 + nt * 16 + lane] = 1023 - (int)(k & 1023u);
    }
#pragma unroll
    for (int o2 = 1; o2 < 64; o2 <<= 1) part += __shfl_xor(part, o2);
    if (lane == 0) lpart[wv] = part;
    __syncthreads();                             // idxf + lpart visible

    // ---- output: gather z_q (exact f32), coalesced 256B-segment stores ----
    // wave wv -> h-row (h0+wv); lane = (cg = lane>>4 channel-group, wq = lane&15)
    const int cg = lane >> 4, wq = lane & 15;
#pragma unroll
    for (int i = 0; i < 16; i++) {
        int cc = i * 4 + cg;
        f32x4 ov;
#pragma unroll
        for (int j = 0; j < 4; j++) {
            int idx = idxf[wv * 64 + wq * 4 + j];
            ov[j] = embed[idx * 64 + cc];         // L2-hot scalar gather
        }
        *(f32x4*)(out + xbase + (size_t)cc * 4096 + wv * 64 + wq * 4) = ov;
    }

    // loss: sum_p dist_min = sum(z^2) + 0.5*256 - 2*sum(acc)
    if (t == 0)
        atomicAdd(loss, (lpart[0] + lpart[1] + lpart[2] + lpart[3] + 128.0f) * LOSS_SCALE);
}

extern "C" void kernel_launch(void* const* d_in, const int* in_sizes, int n_in,
                              void* d_out, int out_size, void* d_ws, size_t ws_size,
                              hipStream_t stream) {
    const float* x     = (const float*)d_in[0];
    const float* embed = (const float*)d_in[1];
    unsigned short* eb = (unsigned short*)d_ws;               // 1024*64 bf16 = 128 KB (swizzled)
    float* c0          = (float*)((char*)d_ws + 131072);      // 1024 f32  = 4 KB
    float* out  = (float*)d_out;
    float* loss = out + TOTAL_ELEMS;

    vq_prep<<<16, 256, 0, stream>>>(embed, eb, c0, loss);
    vq_main<<<512, 256, 0, stream>>>(x, embed, eb, c0, out, loss);
}

// Round 8
// 39.012 us; speedup vs baseline: 1.6058x; 1.6058x over previous
//
#include <hip/hip_runtime.h>

// VQ-VAE quantizer: x[32][64][64][64] f32 NCHW, embed[1024][64] f32
// out: z_q (8388608 f32, NCHW) ++ loss (1 f32),  loss = 1.25*mean((z_q-z)^2)
//
// R8 structure: WHOLE bf16 codebook LDS-resident (128 KB) per block, DMA'd
// once via global_load_lds from pre-swizzled eb. Block = 512 thr = 8 waves =
// 8 h-rows (512 pos), grid 256 = 1 block/CU. z goes straight to B-frag
// registers from global (no z LDS, no staging barrier). Main sweep: 64
// code-tiles, ZERO barriers (R6/R7 were stall-bound on 8+ chunk barriers).
// Lane's own argmin idx recovered from the 4 reduced keys via static selects
// (no idxf LDS). Loss from winning keys (never re-reads x).

#define TOTAL_ELEMS 8388608
#define LOSS_SCALE (1.25f / 8388608.f)

typedef float  f32x4  __attribute__((ext_vector_type(4)));
typedef __bf16 bf16x8 __attribute__((ext_vector_type(8)));
typedef unsigned int u32x4 __attribute__((ext_vector_type(4)));

static __device__ __forceinline__ unsigned short f2bf(float f) {
    unsigned int u = __float_as_uint(f);
    u += 0x7FFFu + ((u >> 16) & 1u);   // round-to-nearest-even
    return (unsigned short)(u >> 16);
}

static __device__ __forceinline__ void gload_lds16(const void* g, void* l) {
    __builtin_amdgcn_global_load_lds(
        (const __attribute__((address_space(1))) void*)g,
        (__attribute__((address_space(3))) void*)l,
        16, 0, 0);
}

// ---- prep: embed f32 -> bf16 PRE-SWIZZLED + c0 = 0.25 - 0.5*||e||^2 ----
__global__ void vq_prep(const float* __restrict__ embed,
                        unsigned short* __restrict__ eb,
                        float* __restrict__ c0,
                        float* __restrict__ loss_slot) {
    int t   = blockIdx.x * 256 + threadIdx.x;   // 0..4095
    int row = t >> 2, qd = t & 3;
    const float* src = embed + row * 64 + qd * 16;
    float s = 0.f;
    unsigned short tmp[16];
#pragma unroll
    for (int i = 0; i < 4; i++) {
        f32x4 v = *(const f32x4*)(src + i * 4);
#pragma unroll
        for (int j = 0; j < 4; j++) {
            float f = v[j];
            s += f * f;
            tmp[i * 4 + j] = f2bf(f);
        }
    }
    u32x4 w0, w1;
#pragma unroll
    for (int i = 0; i < 4; i++) {
        w0[i] = (unsigned)tmp[2*i]   | ((unsigned)tmp[2*i+1] << 16);
        w1[i] = (unsigned)tmp[8+2*i] | ((unsigned)tmp[8+2*i+1] << 16);
    }
    // swizzled store: element (row, byte k2) lives at row*128 + (k2 ^ ((row&7)<<4))
    char* dstb = (char*)eb + row * 128;
    const int sw = (row & 7) << 4;
    *(u32x4*)(dstb + ((qd * 32) ^ sw))      = w0;
    *(u32x4*)(dstb + ((qd * 32 + 16) ^ sw)) = w1;
    s += __shfl_xor(s, 1);
    s += __shfl_xor(s, 2);
    if (qd == 0) c0[row] = 0.25f - 0.5f * s;    // MFMA C-init: acc = z.e + c0 > 0
    if (t == 0) *loss_slot = 0.f;
}

// argmin dist == argmax acc (acc = z.e + 0.25 - ||e||^2/2, strictly positive)
// key = (bits(acc) & ~1023) | (1023 - code)  -> pure u32 max chain
__global__ __launch_bounds__(512, 2) void vq_main(
    const float* __restrict__ x,
    const float* __restrict__ embed,            // f32, for exact gather
    const unsigned short* __restrict__ eb,      // bf16, pre-swizzled rows
    const float* __restrict__ c0,               // f32 per-code C-init
    float* __restrict__ out,
    float* __restrict__ loss) {

    __shared__ __align__(16) unsigned char cb[131072];  // whole codebook, swizzled
    __shared__ __align__(16) float c0l[1024];
    __shared__ float lpart[8];

    const int t    = threadIdx.x;
    const int wv   = t >> 6, lane = t & 63;
    const int l15  = lane & 15, lq = lane >> 4;

    const int blk = blockIdx.x;                  // 0..255 = 32 b x 8 h-groups
    const int b   = blk >> 3;
    const int h0  = (blk & 7) * 8;
    const size_t xbase = (size_t)b * 262144 + (size_t)h0 * 64;

    const char* ebp = (const char*)eb;

    // ---- codebook DMA: wave wv -> cb[wv*16KB, +16KB) (async, no VGPRs) ----
#pragma unroll
    for (int s = 0; s < 16; s++)
        gload_lds16(ebp + wv * 16384 + s * 1024 + lane * 16,
                    &cb[wv * 16384 + s * 1024]);

    // ---- c0 -> LDS (4 KB) ----
    if (t < 256) *(f32x4*)(c0l + t * 4) = *(const f32x4*)(c0 + t * 4);

    // ---- z -> B-frag registers directly (wave wv = h-row h0+wv, w = nt*16+l15,
    //      channel = kh*32 + lq*8 + j); sum z^2 on the fly ----
    float part = 0.f;
    bf16x8 bfr[4][2];
#pragma unroll
    for (int nt = 0; nt < 4; nt++) {
#pragma unroll
        for (int kh = 0; kh < 2; kh++) {
            bf16x8 bb;
#pragma unroll
            for (int j = 0; j < 8; j++) {
                float v = x[xbase + (size_t)(kh * 32 + lq * 8 + j) * 4096
                            + (size_t)wv * 64 + nt * 16 + l15];
                part += v * v;
                bb[j] = (__bf16)v;               // RNE hardware convert
            }
            bfr[nt][kh] = bb;
        }
    }
    __syncthreads();                             // DMA + c0l complete

    // ---- free-running sweep: 64 code-tiles, no barriers ----
    unsigned int key[4] = {0u, 0u, 0u, 0u};
    const int swz = (l15 & 7) << 4;
#pragma unroll 8
    for (int mt = 0; mt < 64; mt++) {
        const unsigned char* rp = &cb[(mt * 16 + l15) * 128];
        bf16x8 a0 = *(const bf16x8*)(rp + ((lq * 16) ^ swz));
        bf16x8 a1 = *(const bf16x8*)(rp + ((64 + lq * 16) ^ swz));
        f32x4 c0v = *(const f32x4*)(c0l + mt * 16 + lq * 4);  // broadcast read
        const int invm = 1023 - mt * 16 - lq * 4;
#pragma unroll
        for (int nt = 0; nt < 4; nt++) {
            f32x4 acc = __builtin_amdgcn_mfma_f32_16x16x32_bf16(a0, bfr[nt][0], c0v, 0, 0, 0);
            acc = __builtin_amdgcn_mfma_f32_16x16x32_bf16(a1, bfr[nt][1], acc, 0, 0, 0);
            // D: col(l15)=pos-in-16-tile, row=(lq*4+r)=code-in-16-tile
#pragma unroll
            for (int r = 0; r < 4; r++) {
                unsigned int k2 = (__float_as_uint(acc[r]) & 0xFFFFFC00u)
                                | (unsigned int)(invm - r);
                key[nt] = key[nt] > k2 ? key[nt] : k2;
            }
        }
    }

    // ---- reduce lq replicas; every lane ends with all 4 final keys ----
#pragma unroll
    for (int nt = 0; nt < 4; nt++) {
        unsigned int k = key[nt];
        unsigned int o = (unsigned int)__shfl_xor((int)k, 16); k = k > o ? k : o;
        o = (unsigned int)__shfl_xor((int)k, 32);              k = k > o ? k : o;
        key[nt] = k;
        // acc_win appears 4x per wave (lq replication): weight -2/4 = -0.5
        part -= 0.5f * __uint_as_float(k & 0xFFFFFC00u);
    }

    // ---- this lane's own position w = lane -> nt = lane>>4 (static selects) ----
    unsigned int klo = (lane & 16) ? key[1] : key[0];
    unsigned int khi = (lane & 16) ? key[3] : key[2];
    unsigned int ks  = (lane & 32) ? khi : klo;
    const int idx = 1023 - (int)(ks & 1023u);

    // ---- loss wave-reduce ----
#pragma unroll
    for (int off = 1; off < 64; off <<= 1) part += __shfl_xor(part, off);
    if (lane == 0) lpart[wv] = part;

    // ---- epilogue: z_q gather (idx fixed per thread -> f32x4 row loads),
    //      stores are 64-lane contiguous 256B lines ----
    const float* erow = embed + idx * 64;
    float* orow = out + xbase + (size_t)wv * 64 + lane;
#pragma unroll
    for (int c4 = 0; c4 < 16; c4++) {
        f32x4 ev = *(const f32x4*)(erow + c4 * 4);
#pragma unroll
        for (int j = 0; j < 4; j++)
            orow[(size_t)(c4 * 4 + j) * 4096] = ev[j];
    }

    __syncthreads();                             // lpart visible
    if (t == 0) {
        float s = 0.f;
#pragma unroll
        for (int i = 0; i < 8; i++) s += lpart[i];
        // sum_p dist_min = sum(z^2) + 0.5*512 - 2*sum(acc)
        atomicAdd(loss, (s + 256.0f) * LOSS_SCALE);
    }
}

extern "C" void kernel_launch(void* const* d_in, const int* in_sizes, int n_in,
                              void* d_out, int out_size, void* d_ws, size_t ws_size,
                              hipStream_t stream) {
    const float* x     = (const float*)d_in[0];
    const float* embed = (const float*)d_in[1];
    unsigned short* eb = (unsigned short*)d_ws;               // 1024*64 bf16 = 128 KB (swizzled)
    float* c0          = (float*)((char*)d_ws + 131072);      // 1024 f32  = 4 KB
    float* out  = (float*)d_out;
    float* loss = out + TOTAL_ELEMS;

    vq_prep<<<16, 256, 0, stream>>>(embed, eb, c0, loss);
    vq_main<<<256, 512, 0, stream>>>(x, embed, eb, c0, out, loss);
}

// Round 9
// 34.751 us; speedup vs baseline: 1.8026x; 1.1226x over previous
//
#include <hip/hip_runtime.h>

// VQ-VAE quantizer: x[32][64][64][64] f32 NCHW, embed[1024][64] f32
// out: z_q (8388608 f32, NCHW) ++ loss (1 f32),  loss = 1.25*mean((z_q-z)^2)
//
// R9: fp8-e4m3 codebook (scaled x1024; embed values are below e4m3's subnormal
// floor unscaled) -> LDS codebook 64 KB -> 2 blocks/CU, 16 waves/CU = 4/SIMD
// (R8's 132 KB pinned us at 2 waves/SIMD; stall-bound). Same zero-barrier
// sweep: whole codebook LDS-resident, DMA'd once (pre-swizzled eb), z straight
// to fp8 B-frags in registers. acc = z.e' + (64 - 512||e||^2) in (9,119) > 0,
// so u32 bit-max on (acc & ~1023) | (1023-code) is argmin dist with smallest-
// index tie-break. Loss: dist = ||z||^2 - acc/512 + 0.125 (never re-reads x).

#define TOTAL_ELEMS 8388608
#define LOSS_SCALE (1.25f / 8388608.f)

typedef float  f32x4  __attribute__((ext_vector_type(4)));
typedef unsigned int u32x2 __attribute__((ext_vector_type(2)));

static __device__ __forceinline__ void gload_lds16(const void* g, void* l) {
    __builtin_amdgcn_global_load_lds(
        (const __attribute__((address_space(1))) void*)g,
        (__attribute__((address_space(3))) void*)l,
        16, 0, 0);
}

// ---- prep: embed f32 -> fp8 e4m3 (x1024), PRE-SWIZZLED; c0 = 64 - 512||e||^2 ----
// swizzle: byte k of row lives at row*64 + (k ^ ((row&7)<<3))  (8B slots)
__global__ void vq_prep(const float* __restrict__ embed,
                        unsigned char* __restrict__ eb,
                        float* __restrict__ c0,
                        float* __restrict__ loss_slot) {
    int t   = blockIdx.x * 256 + threadIdx.x;   // 0..4095
    int row = t >> 2, qd = t & 3;
    const float* src = embed + row * 64 + qd * 16;
    float s = 0.f;
    unsigned int d[4];
#pragma unroll
    for (int i = 0; i < 4; i++) {
        f32x4 v = *(const f32x4*)(src + i * 4);
        s += v[0]*v[0] + v[1]*v[1] + v[2]*v[2] + v[3]*v[3];
        unsigned int r = 0;
        r = __builtin_amdgcn_cvt_pk_fp8_f32(v[0] * 1024.f, v[1] * 1024.f, r, false);
        r = __builtin_amdgcn_cvt_pk_fp8_f32(v[2] * 1024.f, v[3] * 1024.f, r, true);
        d[i] = r;
    }
    char* dstb = (char*)eb + row * 64;
    const int sw = (row & 7) << 3;
    u32x2 lo = {d[0], d[1]}, hi = {d[2], d[3]};
    *(u32x2*)(dstb + ((qd * 16) ^ sw))     = lo;
    *(u32x2*)(dstb + ((qd * 16 + 8) ^ sw)) = hi;
    // reduce sumsq across the 4 threads sharing a row (same wave)
    s += __shfl_xor(s, 1);
    s += __shfl_xor(s, 2);
    if (qd == 0) c0[row] = 64.f - 512.f * s;    // acc = z.(1024e) + c0, in (9,119)
    if (t == 0) *loss_slot = 0.f;
}

// block = 512 thr = 8 waves; wave = 32 positions (nt=2): h-row wv>>1, w-half wv&1
// grid 512 = 32 b x 16 h-groups(4 rows); 2 blocks/CU by LDS (69.7 KB)
__global__ __launch_bounds__(512, 4) void vq_main(
    const float* __restrict__ x,
    const float* __restrict__ embed,            // f32, for exact gather
    const unsigned char* __restrict__ eb,       // fp8, pre-swizzled rows (64 B)
    const float* __restrict__ c0,               // f32 per-code C-init
    float* __restrict__ out,
    float* __restrict__ loss) {

    __shared__ __align__(16) unsigned char cb[65536];  // whole fp8 codebook
    __shared__ __align__(16) float c0l[1024];
    __shared__ float lpart[8];

    const int t    = threadIdx.x;
    const int wv   = t >> 6, lane = t & 63;
    const int l15  = lane & 15, lq = lane >> 4;

    const int blk = blockIdx.x;                  // 0..511
    const int b   = blk >> 4;
    const int h0  = (blk & 15) * 4;
    const size_t xbase = (size_t)b * 262144 + (size_t)h0 * 64;
    const size_t rowoff = (size_t)(wv >> 1) * 64 + (wv & 1) * 32;  // within tile

    const char* ebp = (const char*)eb;

    // ---- codebook DMA (64 KB, async, no VGPRs) ----
#pragma unroll
    for (int s = 0; s < 8; s++)
        gload_lds16(ebp + s * 8192 + t * 16, &cb[s * 8192 + t * 16]);

    // ---- c0 -> LDS (4 KB) ----
    if (t < 256) *(f32x4*)(c0l + t * 4) = *(const f32x4*)(c0 + t * 4);

    // ---- z -> fp8 B-frags in registers; sum z^2 on the fly ----
    // lane covers positions nt*16+l15 (nt=0,1), channels kh*32+lq*8+j
    float part = 0.f;
    unsigned long long bfr[2][2];
#pragma unroll
    for (int nt = 0; nt < 2; nt++) {
#pragma unroll
        for (int kh = 0; kh < 2; kh++) {
            unsigned int dw[2];
#pragma unroll
            for (int p = 0; p < 2; p++) {        // dword pair
                float f[4];
#pragma unroll
                for (int j = 0; j < 4; j++) {
                    f[j] = x[xbase + (size_t)(kh * 32 + lq * 8 + p * 4 + j) * 4096
                             + rowoff + nt * 16 + l15];
                    part += f[j] * f[j];
                }
                unsigned int r = 0;
                r = __builtin_amdgcn_cvt_pk_fp8_f32(f[0], f[1], r, false);
                r = __builtin_amdgcn_cvt_pk_fp8_f32(f[2], f[3], r, true);
                dw[p] = r;
            }
            bfr[nt][kh] = (unsigned long long)dw[0] | ((unsigned long long)dw[1] << 32);
        }
    }
    __syncthreads();                             // DMA + c0l complete

    // ---- free-running sweep: 64 code-tiles, no barriers ----
    unsigned int key[2] = {0u, 0u};
    const int swz = (l15 & 7) << 3;
#pragma unroll 8
    for (int mt = 0; mt < 64; mt++) {
        const unsigned char* rp = &cb[(mt * 16 + l15) * 64];
        long a0 = *(const long*)(rp + ((lq * 8) ^ swz));
        long a1 = *(const long*)(rp + ((32 + lq * 8) ^ swz));
        f32x4 c0v = *(const f32x4*)(c0l + mt * 16 + lq * 4);  // broadcast read
        const int invm = 1023 - mt * 16 - lq * 4;
#pragma unroll
        for (int nt = 0; nt < 2; nt++) {
            f32x4 acc = __builtin_amdgcn_mfma_f32_16x16x32_fp8_fp8(
                a0, (long)bfr[nt][0], c0v, 0, 0, 0);
            acc = __builtin_amdgcn_mfma_f32_16x16x32_fp8_fp8(
                a1, (long)bfr[nt][1], acc, 0, 0, 0);
            // D: col(l15)=pos-in-16-tile, row=(lq*4+r)=code-in-16-tile
#pragma unroll
            for (int r = 0; r < 4; r++) {
                unsigned int k2 = (__float_as_uint(acc[r]) & 0xFFFFFC00u)
                                | (unsigned int)(invm - r);
                key[nt] = key[nt] > k2 ? key[nt] : k2;
            }
        }
    }

    // ---- reduce lq replicas; every lane ends with both final keys ----
#pragma unroll
    for (int nt = 0; nt < 2; nt++) {
        unsigned int k = key[nt];
        unsigned int o = (unsigned int)__shfl_xor((int)k, 16); k = k > o ? k : o;
        o = (unsigned int)__shfl_xor((int)k, 32);              k = k > o ? k : o;
        key[nt] = k;
        // winning acc appears 4x per wave (lq) and on both channel-half lanes:
        // dist = ||z||^2 - acc/512 + 0.125; replication 4 within 64-lane sum
        // over 2 nt covering 32 pos -> each pos counted 4x -> /2048
        part -= (1.f / 2048.f) * __uint_as_float(k & 0xFFFFFC00u);
    }

    // ---- this lane's own position: pos = lane&31 -> nt = (lane>>4)&1 ----
    unsigned int ks = ((lane >> 4) & 1) ? key[1] : key[0];
    const int idx = 1023 - (int)(ks & 1023u);

    // ---- loss wave-reduce ----
#pragma unroll
    for (int off = 1; off < 64; off <<= 1) part += __shfl_xor(part, off);
    if (lane == 0) lpart[wv] = part;

    // ---- epilogue: z_q gather (exact f32; idx fixed per thread), stores are
    //      2x128B contiguous segments per instruction ----
    const int ch0 = (lane >> 5) * 32;            // channel half
    const float* erow = embed + idx * 64 + ch0;
    float* orow = out + xbase + rowoff + (lane & 31) + (size_t)ch0 * 4096;
#pragma unroll
    for (int c4 = 0; c4 < 8; c4++) {
        f32x4 ev = *(const f32x4*)(erow + c4 * 4);
#pragma unroll
        for (int j = 0; j < 4; j++)
            orow[(size_t)(c4 * 4 + j) * 4096] = ev[j];
    }

    __syncthreads();                             // lpart visible
    if (t == 0) {
        float s = 0.f;
#pragma unroll
        for (int i = 0; i < 8; i++) s += lpart[i];
        // sum_p dist = sum(z^2) - sum(acc)/512 + 0.125*256
        atomicAdd(loss, (s + 32.0f) * LOSS_SCALE);
    }
}

extern "C" void kernel_launch(void* const* d_in, const int* in_sizes, int n_in,
                              void* d_out, int out_size, void* d_ws, size_t ws_size,
                              hipStream_t stream) {
    const float* x     = (const float*)d_in[0];
    const float* embed = (const float*)d_in[1];
    unsigned char* eb  = (unsigned char*)d_ws;                // 1024*64 fp8 = 64 KB (swizzled)
    float* c0          = (float*)((char*)d_ws + 65536);       // 1024 f32 = 4 KB
    float* out  = (float*)d_out;
    float* loss = out + TOTAL_ELEMS;

    vq_prep<<<16, 256, 0, stream>>>(embed, eb, c0, loss);
    vq_main<<<512, 512, 0, stream>>>(x, embed, eb, c0, out, loss);
}